// Round 10
// baseline (359.057 us; speedup 1.0000x reference)
//
#include <hip/hip_runtime.h>

#define K 64
#define S_CHUNK 128
#define W_BURN 128

typedef __attribute__((ext_vector_type(2))) _Float16 half2v;
typedef __attribute__((ext_vector_type(8))) _Float16 half8;
typedef __attribute__((ext_vector_type(4))) float f32x4;
typedef __attribute__((ext_vector_type(2))) float f32x2;
typedef __attribute__((ext_vector_type(4))) unsigned u32x4;

#define ONEPK 0x3C003C00u   // {1.0h, 1.0h}

__device__ __forceinline__ float waveReduceSum(float v) {
#pragma unroll
    for (int off = 32; off > 0; off >>= 1) v += __shfl_xor(v, off, 64);
    return v;
}

__device__ __forceinline__ unsigned pkh(float a, float b) {
    auto t = __builtin_amdgcn_cvt_pkrtz(a, b);
    return __builtin_bit_cast(unsigned, t);
}

__device__ __forceinline__ float fdot2(unsigned a, unsigned b, float c) {
#if __has_builtin(__builtin_amdgcn_fdot2)
    return __builtin_amdgcn_fdot2(__builtin_bit_cast(half2v, a),
                                  __builtin_bit_cast(half2v, b), c, false);
#else
    half2v x = __builtin_bit_cast(half2v, a), y = __builtin_bit_cast(half2v, b);
    return c + (float)x[0] * (float)y[0] + (float)x[1] * (float)y[1];
#endif
}

// ws float offsets
#define WS_P     0      // P row-major [64][64] f32 (setup internal)
#define WS_PI    4096
#define WS_UTT0  4160
#define WS_ISG   4224   // 1/sigma
#define WS_NNU   4288   // -mu/sigma
#define WS_L2N   4352   // log2(1/(sigma*sqrt(2pi)))
#define WS_PKP   4480   // u32[64][32]: pkP[s][j2] = {P[2j2][s], P[2j2+1][s]} f16

__global__ __launch_bounds__(64) void hmm_setup(
    const float* __restrict__ y, const float* __restrict__ logits,
    const float* __restrict__ mu, const float* __restrict__ log_sigma,
    float* __restrict__ out, float* __restrict__ ws, int T)
{
    __shared__ float P[K][K];
    __shared__ float pib[K];
    const int k = threadIdx.x;

    float row[K]; float m = -3.4e38f;
#pragma unroll
    for (int i = 0; i < K; ++i) { row[i] = logits[k*K + i]; m = fmaxf(m, row[i]); }
    float s = 0.f;
#pragma unroll
    for (int i = 0; i < K; ++i) { row[i] = __expf(row[i] - m); s += row[i]; }
    float inv = 1.0f / s;
#pragma unroll
    for (int i = 0; i < K; ++i) { float p = row[i]*inv; P[k][i] = p; ws[WS_P + k*K + i] = p; }
    __syncthreads();

    pib[k] = 1.0f/64.0f;
    __syncthreads();
    for (int it = 0; it < 64; ++it) {
        float acc = 0.f;
#pragma unroll
        for (int j = 0; j < K; ++j) acc += pib[j]*P[j][k];   // (pi^T P)_k
        float tot = waveReduceSum(acc);
        acc /= tot;
        __syncthreads();
        pib[k] = acc;
        __syncthreads();
    }
    float pi_k = pib[k];

    // packed P column pairs for the dot2 scan: pkP[k][j2] = {P[2j2][k], P[2j2+1][k]}
    unsigned* wsu = (unsigned*)ws;
#pragma unroll
    for (int j2 = 0; j2 < 32; ++j2)
        wsu[WS_PKP + k*32 + j2] = pkh(P[2*j2][k], P[2*j2+1][k]);

    float mu_k = mu[k];
    float isg = __expf(-log_sigma[k]);            // 1/sigma
    float inorm = isg * 0.39894228040143267f;     // 1/(sigma*sqrt(2pi))

    ws[WS_PI  + k] = pi_k;
    ws[WS_ISG + k] = isg;
    ws[WS_NNU + k] = -mu_k * isg;
    ws[WS_L2N + k] = __log2f(inorm);

    float y0 = y[0];
    float z = (y0 - mu_k) * isg;
    float g0 = __expf(-0.5f*z*z) * inorm;
    float num = pi_k * g0;
    float ft0 = waveReduceSum(num);
    float utt0 = num / ft0;
    ws[WS_UTT0 + k] = utt0;

    out[k] = pi_k;                       // ut[0]
    out[(size_t)T*K + k] = utt0;         // unorm[0]
    if (k == 0) out[(size_t)2*T*K] = ft0;// ft[0]
}

// 2 chunks per wave (one per 32-lane half); lane owns states {2r, 2r+1} of
// its chunk. beta (f16, pow2-lag-scaled) lives in a 128B LDS slot per chunk;
// matvec = 64 v_dot2_f32_f16 from 8 broadcast ds_read_b128. Row-stochastic P
// makes sum(v) = sum(beta): all normalizers are per-lane — zero cross-lane
// ops in the whole loop. SINGLE ROLLED step loop (~1.3KB body): R4-R9's
// structure-independent ~790ns/step at 11% VALUBusy is consistent with the
// 4x-unrolled ~25KB bodies thrashing the per-CU L1 I-cache; a rolled loop
// stays I-cache resident.
__global__ __launch_bounds__(256, 2) void hmm_scan(
    const float* __restrict__ y, const float* __restrict__ ws,
    float* __restrict__ out, int T)
{
    __shared__ __align__(16) unsigned ubuf[4][2][32];  // [wave][half][statepair]
    const int tid  = threadIdx.x;
    const int wid  = tid >> 6;
    const int lane = tid & 63;
    const int h    = lane >> 5;       // which chunk of the wave's pair
    const int r    = lane & 31;       // state-pair index
    const int s0   = 2 * r;
    const int wv   = blockIdx.x * 4 + wid;
    const int cg   = 2 * wv + h;      // this half-wave's chunk
    const int t0   = cg * S_CHUNK;

    const unsigned* wsu = (const unsigned*)ws;

    // P column pairs for states s0, s0+1: 32 u32 each, kept in registers
    u32x4 P0r[8], P1r[8];
    {
        const u32x4* p0 = (const u32x4*)(wsu + WS_PKP + s0 * 32);
        const u32x4* p1 = (const u32x4*)(wsu + WS_PKP + (s0 + 1) * 32);
#pragma unroll
        for (int i = 0; i < 8; ++i) { P0r[i] = p0[i]; P1r[i] = p1[i]; }
    }

    // emission constants for states s0, s0+1
    const float isg0 = ws[WS_ISG + s0], isg1 = ws[WS_ISG + s0 + 1];
    const float nnu0 = ws[WS_NNU + s0], nnu1 = ws[WS_NNU + s0 + 1];
    const float l2n0 = ws[WS_L2N + s0], l2n1 = ws[WS_L2N + s0 + 1];

    unsigned* ub = &ubuf[wid][h][0];
    const u32x4* ubv = (const u32x4*)ub;

    // init beta = pi (f16 pair)
    unsigned myu = pkh(ws[WS_PI + s0], ws[WS_PI + s0 + 1]);
    ub[r] = myu;
    unsigned u0pk = pkh(ws[WS_UTT0 + s0], ws[WS_UTT0 + s0 + 1]);

    const int tlo = (cg == 0) ? 1 : t0;
    const bool is_cg0 = (cg == 0);
    const int t_end = t0 + S_CHUNK;

    float* po = out + (size_t)(t0 - W_BURN) * K + s0;
    float* pu = po + (size_t)T * K;
    float* pf = out + (size_t)2 * T * K + (t0 - W_BURN);

    float rcpPrev = 1.0f, sclPrev = 1.0f;

#pragma unroll 1
    for (int t = t0 - W_BURN; t < t_end; ++t) {
        // y_t for this chunk (clamped; garbage only feeds predicated-off steps
        // or the pre-override cg0 burn)
        int iy = min(max(t, 0), T - 1);
        float yc = y[iy];

        // read u_{t-1} (8x ds_read_b128, uniform per half-wave -> broadcast)
        u32x4 bj[8];
#pragma unroll
        for (int i = 0; i < 8; ++i) bj[i] = ubv[i];

        // su = sum(u_{t-1}) : f16 pairwise tree (depth 2) + 8 f32 dot2
        half8 h0 = __builtin_bit_cast(half8, bj[0]) + __builtin_bit_cast(half8, bj[1]);
        half8 h1 = __builtin_bit_cast(half8, bj[2]) + __builtin_bit_cast(half8, bj[3]);
        half8 h2 = __builtin_bit_cast(half8, bj[4]) + __builtin_bit_cast(half8, bj[5]);
        half8 h3 = __builtin_bit_cast(half8, bj[6]) + __builtin_bit_cast(half8, bj[7]);
        h0 = h0 + h2; h1 = h1 + h3;
        u32x4 w0 = __builtin_bit_cast(u32x4, h0), w1 = __builtin_bit_cast(u32x4, h1);
        float su = 0.f;
        su = fdot2(w0[0], ONEPK, su); su = fdot2(w0[1], ONEPK, su);
        su = fdot2(w0[2], ONEPK, su); su = fdot2(w0[3], ONEPK, su);
        su = fdot2(w1[0], ONEPK, su); su = fdot2(w1[1], ONEPK, su);
        su = fdot2(w1[2], ONEPK, su); su = fdot2(w1[3], ONEPK, su);

        // matvec: v_s = sum_j u_j P[j][s]  (64 dot2, 4 chains)
        float a0 = 0.f, a1 = 0.f, b0 = 0.f, b1 = 0.f;
#pragma unroll
        for (int i = 0; i < 8; ++i) {
            u32x4 w = bj[i];
            a0 = fdot2(w[0], P0r[i][0], a0);  b0 = fdot2(w[0], P1r[i][0], b0);
            a1 = fdot2(w[1], P0r[i][1], a1);  b1 = fdot2(w[1], P1r[i][1], b1);
            a0 = fdot2(w[2], P0r[i][2], a0);  b0 = fdot2(w[2], P1r[i][2], b0);
            a1 = fdot2(w[3], P0r[i][3], a1);  b1 = fdot2(w[3], P1r[i][3], b1);
        }
        float v0 = a0 + a1, v1 = b0 + b1;

        // lag-scale exponent of su; fold 2^-e into the emission
        unsigned sb = __float_as_uint(su);
        int eb = (int)((sb >> 23) & 255u);
        float xf = (float)(126 - eb);                       // -e_t
        float scl = __uint_as_float((unsigned)(eb + 1) << 23); // 2^{e_t}
        float rs = __builtin_amdgcn_rcpf(su);

        // emissions (f32)
        float z0 = fmaf(yc, isg0, nnu0);
        float z1 = fmaf(yc, isg1, nnu1);
        float g0 = __builtin_amdgcn_exp2f(fmaf(z0 * z0, -0.72134752f, l2n0 + xf));
        float g1 = __builtin_amdgcn_exp2f(fmaf(z1 * z1, -0.72134752f, l2n1 + xf));
        float nb0 = v0 * g0, nb1 = v1 * g1;

        // outputs
        const bool outc = (t >= tlo) & (t < T);
        const bool outp = ((t - 1) >= tlo) & ((t - 1) < T);
        if (outc) *(f32x2*)po = f32x2{v0 * rs, v1 * rs};               // ut_t
        if (outp) {
            half2v mu2 = __builtin_bit_cast(half2v, myu);
            *(f32x2*)(pu - K) = f32x2{(float)mu2[0] * rs, (float)mu2[1] * rs}; // unorm_{t-1}
            if (r == 0) pf[-1] = su * rcpPrev * sclPrev;               // ft_{t-1}
        }

        // store u_t
        myu = pkh(nb0, nb1);
        ub[r] = myu;
        rcpPrev = rs; sclPrev = scl;

        // chunk-0: override state after its t=0 step (setup wrote row 0)
        if (is_cg0 & (t == 0)) { myu = u0pk; ub[r] = myu; }

        po += K; pu += K; pf += 1;
    }

    // epilogue: flush lagged outputs for t_end-1
    {
        u32x4 bj[8];
#pragma unroll
        for (int i = 0; i < 8; ++i) bj[i] = ubv[i];
        half8 h0 = __builtin_bit_cast(half8, bj[0]) + __builtin_bit_cast(half8, bj[1]);
        half8 h1 = __builtin_bit_cast(half8, bj[2]) + __builtin_bit_cast(half8, bj[3]);
        half8 h2 = __builtin_bit_cast(half8, bj[4]) + __builtin_bit_cast(half8, bj[5]);
        half8 h3 = __builtin_bit_cast(half8, bj[6]) + __builtin_bit_cast(half8, bj[7]);
        h0 = h0 + h2; h1 = h1 + h3;
        u32x4 w0 = __builtin_bit_cast(u32x4, h0), w1 = __builtin_bit_cast(u32x4, h1);
        float su = 0.f;
        su = fdot2(w0[0], ONEPK, su); su = fdot2(w0[1], ONEPK, su);
        su = fdot2(w0[2], ONEPK, su); su = fdot2(w0[3], ONEPK, su);
        su = fdot2(w1[0], ONEPK, su); su = fdot2(w1[1], ONEPK, su);
        su = fdot2(w1[2], ONEPK, su); su = fdot2(w1[3], ONEPK, su);
        float rs = __builtin_amdgcn_rcpf(su);
        const bool outp = ((t_end - 1) >= tlo) & ((t_end - 1) < T);
        if (outp) {
            half2v mu2 = __builtin_bit_cast(half2v, myu);
            *(f32x2*)(pu - K) = f32x2{(float)mu2[0] * rs, (float)mu2[1] * rs};
            if (r == 0) pf[-1] = su * rcpPrev * sclPrev;
        }
    }
}

extern "C" void kernel_launch(void* const* d_in, const int* in_sizes, int n_in,
                              void* d_out, int out_size, void* d_ws, size_t ws_size,
                              hipStream_t stream) {
    const float* y      = (const float*)d_in[0];
    const float* logits = (const float*)d_in[1];
    const float* mu     = (const float*)d_in[2];
    const float* lsig   = (const float*)d_in[3];
    float* out = (float*)d_out;
    float* ws  = (float*)d_ws;
    const int T = in_sizes[0];

    hmm_setup<<<1, 64, 0, stream>>>(y, logits, mu, lsig, out, ws, T);

    const int nch    = (T + S_CHUNK - 1) / S_CHUNK;   // 7813
    const int nwaves = (nch + 1) / 2;                 // 2 chunks per wave
    const int nblk   = (nwaves + 3) / 4;              // 4 waves per block
    hmm_scan<<<nblk, 256, 0, stream>>>(y, ws, out, T);
}

// Round 11
// 246.243 us; speedup vs baseline: 1.4581x; 1.4581x over previous
//
#include <hip/hip_runtime.h>

#define K 64
#define S_CHUNK 64
#define W_BURN 128
#define BATCH 16
#define NSTEP (S_CHUNK + W_BURN)

typedef __attribute__((ext_vector_type(8))) _Float16 half8;
typedef __attribute__((ext_vector_type(4))) float f32x4;
typedef __attribute__((ext_vector_type(4))) int i32x4;

__device__ __forceinline__ float waveReduceSum(float v) {
#pragma unroll
    for (int off = 32; off > 0; off >>= 1) v += __shfl_xor(v, off, 64);
    return v;
}

__device__ __forceinline__ unsigned pkh(float a, float b) {
    auto t = __builtin_amdgcn_cvt_pkrtz(a, b);
    return __builtin_bit_cast(unsigned, t);
}

// ws float offsets
#define WS_P     0      // P row-major [64][64] f32
#define WS_PI    4096
#define WS_UTT0  4160
#define WS_ISG   4224   // 1/sigma
#define WS_NNU   4288   // -mu/sigma
#define WS_L2N   4352   // log2(1/(sigma*sqrt(2pi)))

__global__ __launch_bounds__(64) void hmm_setup(
    const float* __restrict__ y, const float* __restrict__ logits,
    const float* __restrict__ mu, const float* __restrict__ log_sigma,
    float* __restrict__ out, float* __restrict__ ws, int T)
{
    __shared__ float P[K][K];
    __shared__ float pib[K];
    const int k = threadIdx.x;

    float row[K]; float m = -3.4e38f;
#pragma unroll
    for (int i = 0; i < K; ++i) { row[i] = logits[k*K + i]; m = fmaxf(m, row[i]); }
    float s = 0.f;
#pragma unroll
    for (int i = 0; i < K; ++i) { row[i] = __expf(row[i] - m); s += row[i]; }
    float inv = 1.0f / s;
#pragma unroll
    for (int i = 0; i < K; ++i) { float p = row[i]*inv; P[k][i] = p; ws[WS_P + k*K + i] = p; }
    __syncthreads();

    pib[k] = 1.0f/64.0f;
    __syncthreads();
    for (int it = 0; it < 64; ++it) {
        float acc = 0.f;
#pragma unroll
        for (int j = 0; j < K; ++j) acc += pib[j]*P[j][k];   // (pi^T P)_k
        float tot = waveReduceSum(acc);
        acc /= tot;
        __syncthreads();
        pib[k] = acc;
        __syncthreads();
    }
    float pi_k = pib[k];

    float mu_k = mu[k];
    float isg = __expf(-log_sigma[k]);            // 1/sigma
    float inorm = isg * 0.39894228040143267f;     // 1/(sigma*sqrt(2pi))

    ws[WS_PI  + k] = pi_k;
    ws[WS_ISG + k] = isg;
    ws[WS_NNU + k] = -mu_k * isg;
    ws[WS_L2N + k] = __log2f(inorm);

    float y0 = y[0];
    float z = (y0 - mu_k) * isg;
    float g0 = __expf(-0.5f*z*z) * inorm;
    float num = pi_k * g0;
    float ft0 = waveReduceSum(num);
    float utt0 = num / ft0;
    ws[WS_UTT0 + k] = utt0;

    out[k] = pi_k;                       // ut[0]
    out[(size_t)T*K + k] = utt0;         // unorm[0]
    if (k == 0) out[(size_t)2*T*K] = ft0;// ft[0]
}

// R8's verified step math (8x native mfma_f32_16x16x32_f16, ds_bpermute
// C/D->B redistribution, normalized f16 beta, exact per-step outputs) in a
// SINGLE ROLLED LOOP (~1.5KB body). R10 showed the rolled body unlocks the
// issue pipe (VALUBusy 11->74%): R4-R9's ~25KB unrolled bodies thrashed the
// per-CU L1 I-cache, pinning every structure at ~790ns/step/SIMD. Runtime
// predicates replace the peeled burn/output phases; 1-step y prefetch.
__global__ __launch_bounds__(64, 1) void hmm_scan(
    const float* __restrict__ y, const float* __restrict__ ws,
    float* __restrict__ out, int T)
{
    const int lane = threadIdx.x;
    const int c = lane & 15;          // chunk slot / matrix column
    const int q = lane >> 4;          // lane group
    const int cg = blockIdx.x * BATCH + c;
    const int t0 = cg * S_CHUNK;

    // A fragments (16x16x32): a[nb][kb][j] = P[32kb+8q+j][16nb+c]
    half8 a[4][2];
#pragma unroll
    for (int nb = 0; nb < 4; ++nb)
#pragma unroll
        for (int kb = 0; kb < 2; ++kb)
#pragma unroll
            for (int j = 0; j < 8; ++j)
                a[nb][kb][j] = (_Float16)ws[WS_P + (32*kb + 8*q + j)*K + 16*nb + c];

    // emission constants (C/D layout): s = 16nb + 4q + r
    f32x4 isg_[4], nnu_[4], l2n_[4];
#pragma unroll
    for (int nb = 0; nb < 4; ++nb)
#pragma unroll
        for (int r = 0; r < 4; ++r) {
            int s = 16*nb + 4*q + r;
            isg_[nb][r] = ws[WS_ISG + s];
            nnu_[nb][r] = ws[WS_NNU + s];
            l2n_[nb][r] = ws[WS_L2N + s];
        }

    // B fragments: bfr[kb][j] = beta[32kb + 8q + j] of chunk c
    half8 bfr[2], u0h[2];
#pragma unroll
    for (int kb = 0; kb < 2; ++kb)
#pragma unroll
        for (int j = 0; j < 8; ++j) {
            int s = 32*kb + 8*q + j;
            bfr[kb][j] = (_Float16)ws[WS_PI + s];
            u0h[kb][j] = (_Float16)ws[WS_UTT0 + s];
        }

    const int tlo = (cg == 0) ? 1 : t0;   // burn suppression + cg0 row-0 skip
    int tcur = t0 - W_BURN;

    float* po = out + (long)tcur * K + 4*q;
    float* pu = po + (size_t)T * K;
    float* pf = out + (size_t)2 * T * K + tcur;

    // bpermute byte addresses: src lane 32*(q&1)+c and +16
    const int ad0 = (((lane & 16) << 1) | (lane & 15)) << 2;
    const int ad1 = ad0 + 64;
    const bool hi = (lane >= 32);   // q>>1

    float yc = y[min(max(tcur, 0), T - 1)];

#pragma unroll 1
    for (int i = 0; i < NSTEP; ++i) {
        float yn = y[min(max(tcur + 1, 0), T - 1)];   // prefetch next step's y

        // matvec: acc = P^T u_{t-1}  (8 native MFMA)
        f32x4 acc[4] = {{0.f,0.f,0.f,0.f},{0.f,0.f,0.f,0.f},
                        {0.f,0.f,0.f,0.f},{0.f,0.f,0.f,0.f}};
#pragma unroll
        for (int nb = 0; nb < 4; ++nb)
            acc[nb] = __builtin_amdgcn_mfma_f32_16x16x32_f16(a[nb][0], bfr[0], acc[nb], 0,0,0);
#pragma unroll
        for (int nb = 0; nb < 4; ++nb)
            acc[nb] = __builtin_amdgcn_mfma_f32_16x16x32_f16(a[nb][1], bfr[1], acc[nb], 0,0,0);

        const bool pred = (tcur >= tlo) & (tcur < T);
        if (pred) {
#pragma unroll
            for (int nb = 0; nb < 4; ++nb)
                *(f32x4*)(po + 16*nb) = acc[nb];              // ut_t
        }

        // emissions + filtered update
        f32x4 nrm[4]; float st = 0.f;
#pragma unroll
        for (int nb = 0; nb < 4; ++nb) {
#pragma unroll
            for (int r = 0; r < 4; ++r) {
                float z  = fmaf(yc, isg_[nb][r], nnu_[nb][r]);
                float ag = fmaf(z*z, -0.72134752f, l2n_[nb][r]);
                float g  = __builtin_amdgcn_exp2f(ag);
                nrm[nb][r] = acc[nb][r] * g;
                st += nrm[nb][r];
            }
        }
        st += __shfl_xor(st, 16, 64);
        st += __shfl_xor(st, 32, 64);
        const float rs = __builtin_amdgcn_rcpf(st);
#pragma unroll
        for (int nb = 0; nb < 4; ++nb) nrm[nb] *= rs;
        if (pred) {
#pragma unroll
            for (int nb = 0; nb < 4; ++nb)
                *(f32x4*)(pu + 16*nb) = nrm[nb];              // unorm_t
            if (lane < 16) *pf = st;                          // ft_t
        }

        // pack normalized beta to f16 words
        unsigned p0w0 = pkh(nrm[0][0], nrm[0][1]), p0w1 = pkh(nrm[0][2], nrm[0][3]);
        unsigned p1w0 = pkh(nrm[1][0], nrm[1][1]), p1w1 = pkh(nrm[1][2], nrm[1][3]);
        unsigned p2w0 = pkh(nrm[2][0], nrm[2][1]), p2w1 = pkh(nrm[2][2], nrm[2][3]);
        unsigned p3w0 = pkh(nrm[3][0], nrm[3][1]), p3w1 = pkh(nrm[3][2], nrm[3][3]);
        // redistribute C/D -> B layout: 16 bpermute + 8 select
        int qA0 = __builtin_amdgcn_ds_bpermute(ad0, (int)p0w0);
        int qA1 = __builtin_amdgcn_ds_bpermute(ad0, (int)p0w1);
        int qB0 = __builtin_amdgcn_ds_bpermute(ad0, (int)p1w0);
        int qB1 = __builtin_amdgcn_ds_bpermute(ad0, (int)p1w1);
        int qA2 = __builtin_amdgcn_ds_bpermute(ad1, (int)p0w0);
        int qA3 = __builtin_amdgcn_ds_bpermute(ad1, (int)p0w1);
        int qB2 = __builtin_amdgcn_ds_bpermute(ad1, (int)p1w0);
        int qB3 = __builtin_amdgcn_ds_bpermute(ad1, (int)p1w1);
        int rA0 = __builtin_amdgcn_ds_bpermute(ad0, (int)p2w0);
        int rA1 = __builtin_amdgcn_ds_bpermute(ad0, (int)p2w1);
        int rB0 = __builtin_amdgcn_ds_bpermute(ad0, (int)p3w0);
        int rB1 = __builtin_amdgcn_ds_bpermute(ad0, (int)p3w1);
        int rA2 = __builtin_amdgcn_ds_bpermute(ad1, (int)p2w0);
        int rA3 = __builtin_amdgcn_ds_bpermute(ad1, (int)p2w1);
        int rB2 = __builtin_amdgcn_ds_bpermute(ad1, (int)p3w0);
        int rB3 = __builtin_amdgcn_ds_bpermute(ad1, (int)p3w1);
        i32x4 w0_ = { hi ? qB0 : qA0, hi ? qB1 : qA1,
                      hi ? qB2 : qA2, hi ? qB3 : qA3 };
        i32x4 w1_ = { hi ? rB0 : rA0, hi ? rB1 : rA1,
                      hi ? rB2 : rA2, hi ? rB3 : rA3 };
        bfr[0] = __builtin_bit_cast(half8, w0_);
        bfr[1] = __builtin_bit_cast(half8, w1_);

        // chunk-0 state override after its t=0 step (row 0 written by setup)
        if (__builtin_expect((int)(blockIdx.x == 0) & (int)(i == W_BURN), 0)) {
            if (c == 0) { bfr[0] = u0h[0]; bfr[1] = u0h[1]; }
        }

        yc = yn;
        po += K; pu += K; pf += 1;
        ++tcur;
    }
}

extern "C" void kernel_launch(void* const* d_in, const int* in_sizes, int n_in,
                              void* d_out, int out_size, void* d_ws, size_t ws_size,
                              hipStream_t stream) {
    const float* y      = (const float*)d_in[0];
    const float* logits = (const float*)d_in[1];
    const float* mu     = (const float*)d_in[2];
    const float* lsig   = (const float*)d_in[3];
    float* out = (float*)d_out;
    float* ws  = (float*)d_ws;
    const int T = in_sizes[0];

    hmm_setup<<<1, 64, 0, stream>>>(y, logits, mu, lsig, out, ws, T);

    const int nch  = (T + S_CHUNK - 1) / S_CHUNK;   // 15625
    const int nblk = (nch + BATCH - 1) / BATCH;     // 977
    hmm_scan<<<nblk, 64, 0, stream>>>(y, ws, out, T);
}

// Round 13
// 202.113 us; speedup vs baseline: 1.7765x; 1.2183x over previous
//
#include <hip/hip_runtime.h>

#define K 64
#define S_CHUNK 128
#define W_BURN 96
#define BATCH 16

typedef __attribute__((ext_vector_type(4))) _Float16 half4;
typedef __attribute__((ext_vector_type(4))) float f32x4;

__device__ __forceinline__ float waveReduceSum(float v) {
#pragma unroll
    for (int off = 32; off > 0; off >>= 1) v += __shfl_xor(v, off, 64);
    return v;
}

// ws layout (float offsets)
#define WS_P     0      // P row-major [64][64] f32
#define WS_PI    4096
#define WS_UTT0  4160
#define WS_ISG   4224   // 1/sigma
#define WS_NNU   4288   // -mu/sigma
#define WS_L2N   4352   // log2(1/(sigma*sqrt(2pi)))

__global__ __launch_bounds__(64) void hmm_setup(
    const float* __restrict__ y, const float* __restrict__ logits,
    const float* __restrict__ mu, const float* __restrict__ log_sigma,
    float* __restrict__ out, float* __restrict__ ws, int T)
{
    __shared__ float P[K][K];
    __shared__ float pib[K];
    const int k = threadIdx.x;

    float row[K]; float m = -3.4e38f;
#pragma unroll
    for (int i = 0; i < K; ++i) { row[i] = logits[k*K + i]; m = fmaxf(m, row[i]); }
    float s = 0.f;
#pragma unroll
    for (int i = 0; i < K; ++i) { row[i] = __expf(row[i] - m); s += row[i]; }
    float inv = 1.0f / s;
#pragma unroll
    for (int i = 0; i < K; ++i) { float p = row[i]*inv; P[k][i] = p; ws[WS_P + k*K + i] = p; }
    __syncthreads();

    pib[k] = 1.0f/64.0f;
    __syncthreads();
    for (int it = 0; it < 64; ++it) {
        float acc = 0.f;
#pragma unroll
        for (int j = 0; j < K; ++j) acc += pib[j]*P[j][k];   // (pi^T P)_k
        float tot = waveReduceSum(acc);
        acc /= tot;
        __syncthreads();
        pib[k] = acc;
        __syncthreads();
    }
    float pi_k = pib[k];

    float mu_k = mu[k];
    float isg = __expf(-log_sigma[k]);            // 1/sigma
    float inorm = isg * 0.39894228040143267f;     // 1/(sigma*sqrt(2pi))

    ws[WS_PI  + k] = pi_k;
    ws[WS_ISG + k] = isg;
    ws[WS_NNU + k] = -mu_k * isg;
    ws[WS_L2N + k] = __log2f(inorm);

    float y0 = y[0];
    float z = (y0 - mu_k) * isg;
    float g0 = __expf(-0.5f*z*z) * inorm;
    float num = pi_k * g0;
    float ft0 = waveReduceSum(num);
    float utt0 = num / ft0;
    ws[WS_UTT0 + k] = utt0;

    out[k] = pi_k;                       // ut[0]
    out[(size_t)T*K + k] = utt0;         // unorm[0]
    if (k == 0) out[(size_t)2*T*K] = ft0;// ft[0]
}

// R4 structure verbatim (best passing: 229.6us, 790ns/step at 489 waves):
// one wave = 16 chunks, mfma_f32_16x16x16f16, normalized f16 beta chain,
// serial reduce, cached stores. ONE change: W_BURN 160 -> 96. Evidence:
// absmax is exactly 1.953125e-3 (2^-9) across W=128(f32), W=160(f16),
// W=128(f16) - a W-independent floor; worst case (floor == W=128 residual,
// rho ~ 0.953) gives 0.953^96 ~ 7e-3, still under the 1.02e-2 threshold.
__global__ __launch_bounds__(64) void hmm_scan(
    const float* __restrict__ y, const float* __restrict__ ws,
    float* __restrict__ out, int T)
{
    const int lane = threadIdx.x;
    const int c = lane & 15;          // chunk slot / matrix column
    const int q = lane >> 4;          // lane group
    const int NCH = (T + S_CHUNK - 1) / S_CHUNK;
    (void)NCH;
    const int cg = blockIdx.x * BATCH + c;
    const int t0 = cg * S_CHUNK;

    // A fragments: A(nb,kb)[i][kk] = P[16kb+kk][16nb+i]
    half4 a[4][4];
#pragma unroll
    for (int nb = 0; nb < 4; ++nb)
#pragma unroll
        for (int kb = 0; kb < 4; ++kb)
#pragma unroll
            for (int j = 0; j < 4; ++j)
                a[nb][kb][j] = (_Float16)ws[WS_P + (16*kb + 4*q + j)*K + 16*nb + c];

    f32x4 isg_[4], nnu_[4], l2n_[4];
#pragma unroll
    for (int nb = 0; nb < 4; ++nb)
#pragma unroll
        for (int r = 0; r < 4; ++r) {
            int s = 16*nb + 4*q + r;
            isg_[nb][r] = ws[WS_ISG + s];
            nnu_[nb][r] = ws[WS_NNU + s];
            l2n_[nb][r] = ws[WS_L2N + s];
        }

    half4 bfr[4], u0h[4];
#pragma unroll
    for (int kb = 0; kb < 4; ++kb)
#pragma unroll
        for (int j = 0; j < 4; ++j) {
            int s = 16*kb + 4*q + j;
            bfr[kb][j] = (_Float16)ws[WS_PI + s];
            u0h[kb][j] = (_Float16)ws[WS_UTT0 + s];
        }

    const int tlo = (cg == 0) ? 1 : 0;
    int tcur = t0 - W_BURN;

    float* po = out + (size_t)t0 * K + 4*q;
    float* pu = po + (size_t)T * K;
    float* pf = out + (size_t)2 * T * K + t0;

    int ib = min(max(tcur, 0), T - 4);
    f32x4 yv = *(const f32x4*)(y + ib);

#define STEP(OUTP, YCUR) do {                                                  \
    f32x4 accA_[4] = {{0.f,0.f,0.f,0.f},{0.f,0.f,0.f,0.f},                     \
                      {0.f,0.f,0.f,0.f},{0.f,0.f,0.f,0.f}};                    \
    f32x4 accB_[4] = {{0.f,0.f,0.f,0.f},{0.f,0.f,0.f,0.f},                     \
                      {0.f,0.f,0.f,0.f},{0.f,0.f,0.f,0.f}};                    \
    _Pragma("unroll")                                                          \
    for (int nb_ = 0; nb_ < 4; ++nb_)                                          \
        accA_[nb_] = __builtin_amdgcn_mfma_f32_16x16x16f16(a[nb_][0], bfr[0], accA_[nb_], 0,0,0); \
    _Pragma("unroll")                                                          \
    for (int nb_ = 0; nb_ < 4; ++nb_)                                          \
        accB_[nb_] = __builtin_amdgcn_mfma_f32_16x16x16f16(a[nb_][2], bfr[2], accB_[nb_], 0,0,0); \
    _Pragma("unroll")                                                          \
    for (int nb_ = 0; nb_ < 4; ++nb_)                                          \
        accA_[nb_] = __builtin_amdgcn_mfma_f32_16x16x16f16(a[nb_][1], bfr[1], accA_[nb_], 0,0,0); \
    _Pragma("unroll")                                                          \
    for (int nb_ = 0; nb_ < 4; ++nb_)                                          \
        accB_[nb_] = __builtin_amdgcn_mfma_f32_16x16x16f16(a[nb_][3], bfr[3], accB_[nb_], 0,0,0); \
    const bool pred = (tcur >= tlo) & (tcur < T);                              \
    f32x4 acc_[4];                                                             \
    _Pragma("unroll")                                                          \
    for (int nb_ = 0; nb_ < 4; ++nb_) acc_[nb_] = accA_[nb_] + accB_[nb_];     \
    if (OUTP && pred) {                                                        \
        _Pragma("unroll")                                                      \
        for (int nb_ = 0; nb_ < 4; ++nb_)                                      \
            *(f32x4*)(po + 16*nb_) = acc_[nb_];                                \
    }                                                                          \
    f32x4 nrm[4]; float st = 0.f;                                              \
    _Pragma("unroll")                                                          \
    for (int nb_ = 0; nb_ < 4; ++nb_) {                                        \
        _Pragma("unroll")                                                      \
        for (int r_ = 0; r_ < 4; ++r_) {                                       \
            float z  = fmaf(YCUR, isg_[nb_][r_], nnu_[nb_][r_]);               \
            float ag = fmaf(z*z, -0.72134752f, l2n_[nb_][r_]);                 \
            float g  = __builtin_amdgcn_exp2f(ag);                             \
            nrm[nb_][r_] = acc_[nb_][r_] * g;                                  \
            st += nrm[nb_][r_];                                                \
        }                                                                      \
    }                                                                          \
    st += __shfl_xor(st, 16, 64);                                              \
    st += __shfl_xor(st, 32, 64);                                              \
    const float rs = __builtin_amdgcn_rcpf(st);                                \
    _Pragma("unroll")                                                          \
    for (int nb_ = 0; nb_ < 4; ++nb_) nrm[nb_] *= rs;                          \
    if (OUTP && pred) {                                                        \
        _Pragma("unroll")                                                      \
        for (int nb_ = 0; nb_ < 4; ++nb_)                                      \
            *(f32x4*)(pu + 16*nb_) = nrm[nb_];                                 \
        if (lane < 16) *pf = st;                                               \
    }                                                                          \
    _Pragma("unroll")                                                          \
    for (int kb_ = 0; kb_ < 4; ++kb_) {                                        \
        auto lo_ = __builtin_amdgcn_cvt_pkrtz(nrm[kb_][0], nrm[kb_][1]);       \
        auto hi_ = __builtin_amdgcn_cvt_pkrtz(nrm[kb_][2], nrm[kb_][3]);       \
        bfr[kb_][0] = (_Float16)lo_[0]; bfr[kb_][1] = (_Float16)lo_[1];        \
        bfr[kb_][2] = (_Float16)hi_[0]; bfr[kb_][3] = (_Float16)hi_[1];        \
    }                                                                          \
    if (OUTP) { po += K; pu += K; pf += 1; }                                   \
    ++tcur;                                                                    \
} while (0)

    // burn-in: no stores
#pragma unroll 1
    for (int gi = 0; gi < W_BURN/4; ++gi) {
        int ibn = min(max(tcur + 4, 0), T - 4);
        f32x4 yn = *(const f32x4*)(y + ibn);
        STEP(0, yv[0]); STEP(0, yv[1]); STEP(0, yv[2]); STEP(0, yv[3]);
        yv = yn;
    }
    // first output group (peeled: chunk-0 state override after its t=0 step)
    {
        int ibn = min(max(tcur + 4, 0), T - 4);
        f32x4 yn = *(const f32x4*)(y + ibn);
        STEP(1, yv[0]);
        if (cg == 0) { bfr[0]=u0h[0]; bfr[1]=u0h[1]; bfr[2]=u0h[2]; bfr[3]=u0h[3]; }
        STEP(1, yv[1]); STEP(1, yv[2]); STEP(1, yv[3]);
        yv = yn;
    }
#pragma unroll 1
    for (int gi = 1; gi < S_CHUNK/4; ++gi) {
        int ibn = min(max(tcur + 4, 0), T - 4);
        f32x4 yn = *(const f32x4*)(y + ibn);
        STEP(1, yv[0]); STEP(1, yv[1]); STEP(1, yv[2]); STEP(1, yv[3]);
        yv = yn;
    }
#undef STEP
}

extern "C" void kernel_launch(void* const* d_in, const int* in_sizes, int n_in,
                              void* d_out, int out_size, void* d_ws, size_t ws_size,
                              hipStream_t stream) {
    const float* y      = (const float*)d_in[0];
    const float* logits = (const float*)d_in[1];
    const float* mu     = (const float*)d_in[2];
    const float* lsig   = (const float*)d_in[3];
    float* out = (float*)d_out;
    float* ws  = (float*)d_ws;
    const int T = in_sizes[0];

    hmm_setup<<<1, 64, 0, stream>>>(y, logits, mu, lsig, out, ws, T);

    const int nch  = (T + S_CHUNK - 1) / S_CHUNK;
    const int nblk = (nch + BATCH - 1) / BATCH;
    hmm_scan<<<nblk, 64, 0, stream>>>(y, ws, out, T);
}